// Round 3
// baseline (598.405 us; speedup 1.0000x reference)
//
#include <hip/hip_runtime.h>

#define NN 50000
#define NE 800000
#define C 128
#define H 16
#define NB 8          // nodes per fused block
#define NTILE (NN / NB)

// ---------- silu + 7 cubic B-spline bases (efficient-KAN grid, knots -2.5+0.5j) ----------
__device__ __forceinline__ void feat8(float x, float* o) {
  o[0] = x / (1.f + __expf(-x));
  float b[10];
#pragma unroll
  for (int j = 0; j < 10; ++j) {
    float gj = -2.5f + 0.5f * j;
    b[j] = (x >= gj && x < gj + 0.5f) ? 1.f : 0.f;
  }
#pragma unroll
  for (int p = 1; p <= 3; ++p) {
    float invd = (p == 1) ? 2.f : (p == 2) ? 1.f : (1.f / 1.5f);
#pragma unroll
    for (int j = 0; j < 10 - p; ++j) {
      float gj = -2.5f + 0.5f * j;
      b[j] = (x - gj) * invd * b[j] + ((gj + 0.5f * (p + 1)) - x) * invd * b[j + 1];
    }
  }
#pragma unroll
  for (int j = 0; j < 7; ++j) o[1 + j] = b[j];
}

// ---------- pack (base_w, spline_w*scaler) as 8-float records ----------
__global__ void prep_kernel(const float* __restrict__ bw0, const float* __restrict__ sw0,
                            const float* __restrict__ sc0,
                            const float* __restrict__ bw1, const float* __restrict__ sw1,
                            const float* __restrict__ sc1,
                            float* __restrict__ pack0, float* __restrict__ pack1) {
  int i = blockIdx.x * blockDim.x + threadIdx.x;
  if (i < H * C * 8) {
    int of = i >> 3, j = i & 7;
    pack0[i] = (j == 0) ? bw0[of] : sw0[of * 7 + (j - 1)] * sc0[of];
  }
  if (i < C * H * 8) {
    int of = i >> 3, j = i & 7;
    pack1[i] = (j == 0) ? bw1[of] : sw1[of * 7 + (j - 1)] * sc1[of];
  }
}

// ---------- in-degree count ----------
__global__ void count_kernel(const int* __restrict__ dst, int* __restrict__ cnt) {
  int e = blockIdx.x * blockDim.x + threadIdx.x;
  if (e < NE) atomicAdd(&cnt[dst[e]], 1);
}

// ---------- hierarchical exclusive scan ----------
__global__ void scan1(const int* __restrict__ cnt, int* __restrict__ excl,
                      int* __restrict__ bsums, int n) {
  int i = blockIdx.x * 256 + threadIdx.x;
  int v = (i < n) ? cnt[i] : 0;
  int lane = threadIdx.x & 63, wid = threadIdx.x >> 6;
  int s = v;
#pragma unroll
  for (int o = 1; o < 64; o <<= 1) {
    int t = __shfl_up(s, o, 64);
    if (lane >= o) s += t;
  }
  __shared__ int wsum[4];
  if (lane == 63) wsum[wid] = s;
  __syncthreads();
  int woff = 0;
  for (int w = 0; w < wid; ++w) woff += wsum[w];
  if (i < n) excl[i] = woff + s - v;
  if (threadIdx.x == 255) bsums[blockIdx.x] = woff + s;
}

__global__ void scan2(int* __restrict__ bsums, int nb) {
  int i = threadIdx.x;
  int v = (i < nb) ? bsums[i] : 0;
  int lane = threadIdx.x & 63, wid = threadIdx.x >> 6;
  int s = v;
#pragma unroll
  for (int o = 1; o < 64; o <<= 1) {
    int t = __shfl_up(s, o, 64);
    if (lane >= o) s += t;
  }
  __shared__ int wsum[4];
  if (lane == 63) wsum[wid] = s;
  __syncthreads();
  int woff = 0;
  for (int w = 0; w < wid; ++w) woff += wsum[w];
  if (i < nb) bsums[i] = woff + s - v;
}

__global__ void scan3(const int* __restrict__ excl, const int* __restrict__ bsums,
                      const int* __restrict__ cnt, int* __restrict__ row_start,
                      float* __restrict__ dinv, int n) {
  int i = blockIdx.x * 256 + threadIdx.x;
  if (i < n) {
    row_start[i] = excl[i] + bsums[blockIdx.x];
    dinv[i] = rsqrtf((float)(cnt[i] + 1));  // +1 self-loop => deg >= 1
  }
  if (blockIdx.x == 0 && threadIdx.x == 0) row_start[n] = NE;
}

// ---------- CSR fill (also pre-folds dinv[src] into a per-slot weight) ----------
__global__ void fill_kernel(const int* __restrict__ src, const int* __restrict__ dst,
                            const int* __restrict__ row_start, const float* __restrict__ dinv,
                            int* __restrict__ fillcnt, int* __restrict__ csr,
                            float* __restrict__ csrw) {
  int e = blockIdx.x * blockDim.x + threadIdx.x;
  if (e < NE) {
    int d = dst[e];
    int s = src[e];
    int p = atomicAdd(&fillcnt[d], 1);
    int slot = row_start[d] + p;
    csr[slot] = s;
    csrw[slot] = dinv[s];
  }
}

// ---------- fully fused: aggregate(x) -> GEMV(W) -> KAN0 -> KAN1 -> f32 out ----------
// Uses GCN identity  A_norm (X W^T) = (A_norm X) W^T  to avoid materializing h.
__global__ __launch_bounds__(256) void fused_all(
    const float* __restrict__ x, const float* __restrict__ W,
    const float* __restrict__ bias,
    const int* __restrict__ csr, const float* __restrict__ csrw,
    const int* __restrict__ row_start, const float* __restrict__ dinv,
    const float* __restrict__ pack0, const float* __restrict__ pack1,
    float* __restrict__ out) {
  __shared__ float ax[NB][C];          // 4 KB
  __shared__ float feat0[NB][C][8];    // 32 KB
  __shared__ float hid[NB][H];
  __shared__ float feat1[NB][H][8];    // 4 KB
  const int tid = threadIdx.x;
  const int n0 = blockIdx.x * NB;

  // ---- phase 1: normalized aggregation of raw x rows (2 nodes concurrent) ----
  {
    const int c = tid & 127;
    const int half = tid >> 7;
#pragma unroll
    for (int r = 0; r < 4; ++r) {
      const int nn = r * 2 + half;
      const int node = n0 + nn;
      const int e0 = row_start[node], e1 = row_start[node + 1];
      const float dn = dinv[node];
      float a = x[(size_t)node * C + c] * (dn * dn);  // self loop
      for (int e = e0; e < e1; ++e) {
        a += x[(size_t)csr[e] * C + c] * (csrw[e] * dn);
      }
      ax[nn][c] = a;
    }
  }
  __syncthreads();

  // ---- phase 2: GEMV h[nn][o] = W[o][:] . ax[nn][:] + bias[o]; feat8 -> feat0 ----
  {
    const int o = tid & 127;
    const int ng = tid >> 7;  // node group: nodes ng*4 .. ng*4+3
    float acc0 = 0.f, acc1 = 0.f, acc2 = 0.f, acc3 = 0.f;
    const float4* wr = (const float4*)&W[o * C];
#pragma unroll 8
    for (int k4 = 0; k4 < 32; ++k4) {
      const float4 w = wr[k4];
      const float4 a0 = *(const float4*)&ax[ng * 4 + 0][k4 * 4];
      const float4 a1 = *(const float4*)&ax[ng * 4 + 1][k4 * 4];
      const float4 a2 = *(const float4*)&ax[ng * 4 + 2][k4 * 4];
      const float4 a3 = *(const float4*)&ax[ng * 4 + 3][k4 * 4];
      acc0 += w.x * a0.x + w.y * a0.y + w.z * a0.z + w.w * a0.w;
      acc1 += w.x * a1.x + w.y * a1.y + w.z * a1.z + w.w * a1.w;
      acc2 += w.x * a2.x + w.y * a2.y + w.z * a2.z + w.w * a2.w;
      acc3 += w.x * a3.x + w.y * a3.y + w.z * a3.z + w.w * a3.w;
    }
    const float b = bias[o];
    float hv[4] = {acc0 + b, acc1 + b, acc2 + b, acc3 + b};
#pragma unroll
    for (int j = 0; j < 4; ++j) {
      float fb[8];
      feat8(hv[j], fb);
      const int nn = ng * 4 + j;
      *(float4*)&feat0[nn][o][0] = make_float4(fb[0], fb[1], fb[2], fb[3]);
      *(float4*)&feat0[nn][o][4] = make_float4(fb[4], fb[5], fb[6], fb[7]);
    }
  }
  __syncthreads();

  // ---- phase 3: KAN0  hid[nn][o1] = sum_f feat0[nn][f][:] . pack0[o1][f][:] ----
  {
    const int o1 = tid >> 4, l = tid & 15;  // tid = o1*16 + l, 16 lanes per output
    float acc[NB];
#pragma unroll
    for (int nn = 0; nn < NB; ++nn) acc[nn] = 0.f;
#pragma unroll
    for (int i = 0; i < 8; ++i) {
      const int f = l + 16 * i;
      const float4* wp = (const float4*)&pack0[(o1 * C + f) * 8];
      const float4 g0 = wp[0], g1 = wp[1];
#pragma unroll
      for (int nn = 0; nn < NB; ++nn) {
        const float4 F0 = *(const float4*)&feat0[nn][f][0];
        const float4 F1 = *(const float4*)&feat0[nn][f][4];
        acc[nn] += F0.x * g0.x + F0.y * g0.y + F0.z * g0.z + F0.w * g0.w
                 + F1.x * g1.x + F1.y * g1.y + F1.z * g1.z + F1.w * g1.w;
      }
    }
#pragma unroll
    for (int nn = 0; nn < NB; ++nn) {
      acc[nn] += __shfl_down(acc[nn], 8, 16);
      acc[nn] += __shfl_down(acc[nn], 4, 16);
      acc[nn] += __shfl_down(acc[nn], 2, 16);
      acc[nn] += __shfl_down(acc[nn], 1, 16);
    }
    if (l == 0) {
#pragma unroll
      for (int nn = 0; nn < NB; ++nn) hid[nn][o1] = acc[nn];
    }
  }
  __syncthreads();

  // ---- phase 4: feat8 of the 8x16 hidden values ----
  if (tid < NB * H) {
    const int nn = tid >> 4, j = tid & 15;
    float fb[8];
    feat8(hid[nn][j], fb);
    *(float4*)&feat1[nn][j][0] = make_float4(fb[0], fb[1], fb[2], fb[3]);
    *(float4*)&feat1[nn][j][4] = make_float4(fb[4], fb[5], fb[6], fb[7]);
  }
  __syncthreads();

  // ---- phase 5: KAN1 + f32 store ----
  {
    const int o = tid & 127, ng = tid >> 7;
    float acc[4] = {0.f, 0.f, 0.f, 0.f};
#pragma unroll
    for (int f = 0; f < H; ++f) {
      const float4* wp = (const float4*)&pack1[(o * H + f) * 8];
      const float4 g0 = wp[0], g1 = wp[1];
#pragma unroll
      for (int j = 0; j < 4; ++j) {
        const int nn = ng * 4 + j;
        const float4 F0 = *(const float4*)&feat1[nn][f][0];
        const float4 F1 = *(const float4*)&feat1[nn][f][4];
        acc[j] += F0.x * g0.x + F0.y * g0.y + F0.z * g0.z + F0.w * g0.w
                + F1.x * g1.x + F1.y * g1.y + F1.z * g1.z + F1.w * g1.w;
      }
    }
#pragma unroll
    for (int j = 0; j < 4; ++j) {
      const int nn = ng * 4 + j;
      out[(size_t)(n0 + nn) * C + o] = acc[j];
    }
  }
}

extern "C" void kernel_launch(void* const* d_in, const int* in_sizes, int n_in,
                              void* d_out, int out_size, void* d_ws, size_t ws_size,
                              hipStream_t stream) {
  const float* x   = (const float*)d_in[0];
  const int*   ei  = (const int*)d_in[1];
  const float* gw  = (const float*)d_in[2];
  const float* gb  = (const float*)d_in[3];
  const float* bw0 = (const float*)d_in[4];
  const float* sw0 = (const float*)d_in[5];
  const float* sc0 = (const float*)d_in[6];
  const float* bw1 = (const float*)d_in[7];
  const float* sw1 = (const float*)d_in[8];
  const float* sc1 = (const float*)d_in[9];
  float* out = (float*)d_out;   // reference output dtype is float32

  // compact workspace: ~7.5 MB total
  char* p = (char*)d_ws;
  float* pack0 = (float*)p;   p += H * C * 8 * 4;      // 64 KB
  float* pack1 = (float*)p;   p += C * H * 8 * 4;      // 64 KB
  float* dinv = (float*)p;    p += NN * 4;             // 200 KB
  int* cnt = (int*)p;         p += NN * 4;
  int* excl = (int*)p;        p += NN * 4;
  int* fillcnt = (int*)p;     p += NN * 4;
  int* bsums = (int*)p;       p += 256 * 4;
  int* row_start = (int*)p;   p += (NN + 1) * 4;
  int* csr = (int*)p;         p += (size_t)NE * 4;     // 3.2 MB
  float* csrw = (float*)p;    p += (size_t)NE * 4;     // 3.2 MB

  const int* src = ei;
  const int* dst = ei + NE;

  hipMemsetAsync(cnt, 0, NN * 4, stream);
  hipMemsetAsync(fillcnt, 0, NN * 4, stream);

  prep_kernel<<<64, 256, 0, stream>>>(bw0, sw0, sc0, bw1, sw1, sc1, pack0, pack1);
  count_kernel<<<(NE + 255) / 256, 256, 0, stream>>>(dst, cnt);
  scan1<<<196, 256, 0, stream>>>(cnt, excl, bsums, NN);
  scan2<<<1, 256, 0, stream>>>(bsums, 196);
  scan3<<<196, 256, 0, stream>>>(excl, bsums, cnt, row_start, dinv, NN);
  fill_kernel<<<(NE + 255) / 256, 256, 0, stream>>>(src, dst, row_start, dinv, fillcnt, csr, csrw);
  fused_all<<<NTILE, 256, 0, stream>>>(x, gw, gb, csr, csrw, row_start, dinv,
                                       pack0, pack1, out);
}

// Round 4
// 543.474 us; speedup vs baseline: 1.1011x; 1.1011x over previous
//
#include <hip/hip_runtime.h>

#define NN 50000
#define NE 800000
#define C 128
#define H 16

// ---------- silu + 7 cubic B-spline bases (efficient-KAN grid, knots -2.5+0.5j) ----------
__device__ __forceinline__ void feat8(float x, float* o) {
  o[0] = x / (1.f + __expf(-x));
  float b[10];
#pragma unroll
  for (int j = 0; j < 10; ++j) {
    float gj = -2.5f + 0.5f * j;
    b[j] = (x >= gj && x < gj + 0.5f) ? 1.f : 0.f;
  }
#pragma unroll
  for (int p = 1; p <= 3; ++p) {
    float invd = (p == 1) ? 2.f : (p == 2) ? 1.f : (1.f / 1.5f);
#pragma unroll
    for (int j = 0; j < 10 - p; ++j) {
      float gj = -2.5f + 0.5f * j;
      b[j] = (x - gj) * invd * b[j] + ((gj + 0.5f * (p + 1)) - x) * invd * b[j + 1];
    }
  }
#pragma unroll
  for (int j = 0; j < 7; ++j) o[1 + j] = b[j];
}

// ---------- pack (base_w, spline_w*scaler) as 8-float records ----------
__global__ void prep_kernel(const float* __restrict__ bw0, const float* __restrict__ sw0,
                            const float* __restrict__ sc0,
                            const float* __restrict__ bw1, const float* __restrict__ sw1,
                            const float* __restrict__ sc1,
                            float* __restrict__ pack0, float* __restrict__ pack1) {
  int i = blockIdx.x * blockDim.x + threadIdx.x;
  if (i < H * C * 8) {
    int of = i >> 3, j = i & 7;
    pack0[i] = (j == 0) ? bw0[of] : sw0[of * 7 + (j - 1)] * sc0[of];
  }
  if (i < C * H * 8) {
    int of = i >> 3, j = i & 7;
    pack1[i] = (j == 0) ? bw1[of] : sw1[of * 7 + (j - 1)] * sc1[of];
  }
}

// ---------- in-degree count ----------
__global__ void count_kernel(const int* __restrict__ dst, int* __restrict__ cnt) {
  int e = blockIdx.x * blockDim.x + threadIdx.x;
  if (e < NE) atomicAdd(&cnt[dst[e]], 1);
}

// ---------- hierarchical exclusive scan ----------
__global__ void scan1(const int* __restrict__ cnt, int* __restrict__ excl,
                      int* __restrict__ bsums, int n) {
  int i = blockIdx.x * 256 + threadIdx.x;
  int v = (i < n) ? cnt[i] : 0;
  int lane = threadIdx.x & 63, wid = threadIdx.x >> 6;
  int s = v;
#pragma unroll
  for (int o = 1; o < 64; o <<= 1) {
    int t = __shfl_up(s, o, 64);
    if (lane >= o) s += t;
  }
  __shared__ int wsum[4];
  if (lane == 63) wsum[wid] = s;
  __syncthreads();
  int woff = 0;
  for (int w = 0; w < wid; ++w) woff += wsum[w];
  if (i < n) excl[i] = woff + s - v;
  if (threadIdx.x == 255) bsums[blockIdx.x] = woff + s;
}

__global__ void scan2(int* __restrict__ bsums, int nb) {
  int i = threadIdx.x;
  int v = (i < nb) ? bsums[i] : 0;
  int lane = threadIdx.x & 63, wid = threadIdx.x >> 6;
  int s = v;
#pragma unroll
  for (int o = 1; o < 64; o <<= 1) {
    int t = __shfl_up(s, o, 64);
    if (lane >= o) s += t;
  }
  __shared__ int wsum[4];
  if (lane == 63) wsum[wid] = s;
  __syncthreads();
  int woff = 0;
  for (int w = 0; w < wid; ++w) woff += wsum[w];
  if (i < nb) bsums[i] = woff + s - v;
}

__global__ void scan3(const int* __restrict__ excl, const int* __restrict__ bsums,
                      const int* __restrict__ cnt, int* __restrict__ row_start,
                      float* __restrict__ dinv, int n) {
  int i = blockIdx.x * 256 + threadIdx.x;
  if (i < n) {
    row_start[i] = excl[i] + bsums[blockIdx.x];
    dinv[i] = rsqrtf((float)(cnt[i] + 1));  // +1 self-loop => deg >= 1
  }
  if (blockIdx.x == 0 && threadIdx.x == 0) row_start[n] = NE;
}

// ---------- CSR fill; csrw pre-folds dinv[src]*dinv[dst] ----------
__global__ void fill_kernel(const int* __restrict__ src, const int* __restrict__ dst,
                            const int* __restrict__ row_start, const float* __restrict__ dinv,
                            int* __restrict__ fillcnt, int* __restrict__ csr,
                            float* __restrict__ csrw) {
  int e = blockIdx.x * blockDim.x + threadIdx.x;
  if (e < NE) {
    int d = dst[e];
    int s = src[e];
    int p = atomicAdd(&fillcnt[d], 1);
    int slot = row_start[d] + p;
    csr[slot] = s;
    csrw[slot] = dinv[s] * dinv[d];
  }
}

// ---------- aggregation: ax[node][c] = sum over in-edges (norm-weighted) ----------
// 2 nodes/block, no LDS, max occupancy; edge loop unrolled x4 for MLP.
__global__ __launch_bounds__(256, 8) void agg_kernel(
    const float* __restrict__ x, const int* __restrict__ csr,
    const float* __restrict__ csrw, const int* __restrict__ row_start,
    const float* __restrict__ dinv, float* __restrict__ ax) {
  const int c = threadIdx.x & 127;
  const int node = blockIdx.x * 2 + (threadIdx.x >> 7);
  const int e0 = row_start[node], e1 = row_start[node + 1];
  const float dn = dinv[node];
  float a = x[(size_t)node * C + c] * (dn * dn);  // self loop
  int e = e0;
  for (; e + 4 <= e1; e += 4) {
    const int s0 = csr[e], s1 = csr[e + 1], s2 = csr[e + 2], s3 = csr[e + 3];
    const float w0 = csrw[e], w1 = csrw[e + 1], w2 = csrw[e + 2], w3 = csrw[e + 3];
    const float x0 = x[(size_t)s0 * C + c];
    const float x1 = x[(size_t)s1 * C + c];
    const float x2 = x[(size_t)s2 * C + c];
    const float x3 = x[(size_t)s3 * C + c];
    a += x0 * w0;
    a += x1 * w1;
    a += x2 * w2;
    a += x3 * w3;
  }
  for (; e < e1; ++e) a += x[(size_t)csr[e] * C + c] * csrw[e];
  ax[(size_t)node * C + c] = a;
}

// ---------- KAN stack: GEMV(W) -> feat8 -> KAN0 -> feat8 -> KAN1 -> f32 out ----------
// 4 nodes/block, 256 threads, LDS ~20.3 KB -> 7 blocks/CU.
__global__ __launch_bounds__(256, 6) void kan_kernel(
    const float* __restrict__ ax, const float* __restrict__ W,
    const float* __restrict__ bias, const float* __restrict__ pack0,
    const float* __restrict__ pack1, float* __restrict__ out) {
  __shared__ float axs[4][C];          // 2 KB
  __shared__ float feat0[4][C][8];     // 16 KB
  __shared__ float hid[4][H];
  __shared__ float feat1[4][H][8];     // 2 KB
  const int tid = threadIdx.x;
  const int n0 = blockIdx.x * 4;

  // stage ax tile (512 contiguous floats, coalesced)
  *(float2*)&((float*)axs)[tid * 2] =
      *(const float2*)&ax[(size_t)n0 * C + tid * 2];
  __syncthreads();

  // ---- GEMV + feat8: thread (o, ng) handles nodes ng*2, ng*2+1 ----
  {
    const int o = tid & 127;
    const int ng = tid >> 7;
    float acc0 = 0.f, acc1 = 0.f;
    const float4* wr = (const float4*)&W[o * C];
#pragma unroll 8
    for (int k4 = 0; k4 < 32; ++k4) {
      const float4 w = wr[k4];
      const float4 a0 = *(const float4*)&axs[ng * 2 + 0][k4 * 4];
      const float4 a1 = *(const float4*)&axs[ng * 2 + 1][k4 * 4];
      acc0 += w.x * a0.x + w.y * a0.y + w.z * a0.z + w.w * a0.w;
      acc1 += w.x * a1.x + w.y * a1.y + w.z * a1.z + w.w * a1.w;
    }
    const float b = bias[o];
    float hv[2] = {acc0 + b, acc1 + b};
#pragma unroll
    for (int j = 0; j < 2; ++j) {
      float fb[8];
      feat8(hv[j], fb);
      const int nn = ng * 2 + j;
      *(float4*)&feat0[nn][o][0] = make_float4(fb[0], fb[1], fb[2], fb[3]);
      *(float4*)&feat0[nn][o][4] = make_float4(fb[4], fb[5], fb[6], fb[7]);
    }
  }
  __syncthreads();

  // ---- KAN0: tid = o1*16 + l, 16 lanes per hidden output ----
  {
    const int o1 = tid >> 4, l = tid & 15;
    float acc[4] = {0.f, 0.f, 0.f, 0.f};
#pragma unroll
    for (int i = 0; i < 8; ++i) {
      const int f = l + 16 * i;
      const float4* wp = (const float4*)&pack0[(o1 * C + f) * 8];
      const float4 g0 = wp[0], g1 = wp[1];
#pragma unroll
      for (int nn = 0; nn < 4; ++nn) {
        const float4 F0 = *(const float4*)&feat0[nn][f][0];
        const float4 F1 = *(const float4*)&feat0[nn][f][4];
        acc[nn] += F0.x * g0.x + F0.y * g0.y + F0.z * g0.z + F0.w * g0.w
                 + F1.x * g1.x + F1.y * g1.y + F1.z * g1.z + F1.w * g1.w;
      }
    }
#pragma unroll
    for (int nn = 0; nn < 4; ++nn) {
      acc[nn] += __shfl_down(acc[nn], 8, 16);
      acc[nn] += __shfl_down(acc[nn], 4, 16);
      acc[nn] += __shfl_down(acc[nn], 2, 16);
      acc[nn] += __shfl_down(acc[nn], 1, 16);
    }
    if (l == 0) {
#pragma unroll
      for (int nn = 0; nn < 4; ++nn) hid[nn][o1] = acc[nn];
    }
  }
  __syncthreads();

  // ---- feat8 of the 4x16 hidden values ----
  if (tid < 4 * H) {
    const int nn = tid >> 4, j = tid & 15;
    float fb[8];
    feat8(hid[nn][j], fb);
    *(float4*)&feat1[nn][j][0] = make_float4(fb[0], fb[1], fb[2], fb[3]);
    *(float4*)&feat1[nn][j][4] = make_float4(fb[4], fb[5], fb[6], fb[7]);
  }
  __syncthreads();

  // ---- KAN1 + f32 store ----
  {
    const int o = tid & 127, ng = tid >> 7;
    float acc[2] = {0.f, 0.f};
#pragma unroll
    for (int f = 0; f < H; ++f) {
      const float4* wp = (const float4*)&pack1[(o * H + f) * 8];
      const float4 g0 = wp[0], g1 = wp[1];
#pragma unroll
      for (int j = 0; j < 2; ++j) {
        const int nn = ng * 2 + j;
        const float4 F0 = *(const float4*)&feat1[nn][f][0];
        const float4 F1 = *(const float4*)&feat1[nn][f][4];
        acc[j] += F0.x * g0.x + F0.y * g0.y + F0.z * g0.z + F0.w * g0.w
                + F1.x * g1.x + F1.y * g1.y + F1.z * g1.z + F1.w * g1.w;
      }
    }
#pragma unroll
    for (int j = 0; j < 2; ++j) {
      const int nn = ng * 2 + j;
      out[(size_t)(n0 + nn) * C + o] = acc[j];
    }
  }
}

extern "C" void kernel_launch(void* const* d_in, const int* in_sizes, int n_in,
                              void* d_out, int out_size, void* d_ws, size_t ws_size,
                              hipStream_t stream) {
  const float* x   = (const float*)d_in[0];
  const int*   ei  = (const int*)d_in[1];
  const float* gw  = (const float*)d_in[2];
  const float* gb  = (const float*)d_in[3];
  const float* bw0 = (const float*)d_in[4];
  const float* sw0 = (const float*)d_in[5];
  const float* sc0 = (const float*)d_in[6];
  const float* bw1 = (const float*)d_in[7];
  const float* sw1 = (const float*)d_in[8];
  const float* sc1 = (const float*)d_in[9];
  float* out = (float*)d_out;   // reference output dtype is float32

  // workspace: ~33 MB
  char* p = (char*)d_ws;
  float* pack0 = (float*)p;   p += H * C * 8 * 4;      // 64 KB
  float* pack1 = (float*)p;   p += C * H * 8 * 4;      // 64 KB
  float* dinv = (float*)p;    p += NN * 4;
  int* cnt = (int*)p;         p += NN * 4;
  int* excl = (int*)p;        p += NN * 4;
  int* fillcnt = (int*)p;     p += NN * 4;
  int* bsums = (int*)p;       p += 256 * 4;
  int* row_start = (int*)p;   p += (NN + 1) * 4;
  int* csr = (int*)p;         p += (size_t)NE * 4;     // 3.2 MB
  float* csrw = (float*)p;    p += (size_t)NE * 4;     // 3.2 MB
  float* ax = (float*)p;      p += (size_t)NN * C * 4; // 25.6 MB

  const int* src = ei;
  const int* dst = ei + NE;

  hipMemsetAsync(cnt, 0, NN * 4, stream);
  hipMemsetAsync(fillcnt, 0, NN * 4, stream);

  prep_kernel<<<64, 256, 0, stream>>>(bw0, sw0, sc0, bw1, sw1, sc1, pack0, pack1);
  count_kernel<<<(NE + 255) / 256, 256, 0, stream>>>(dst, cnt);
  scan1<<<196, 256, 0, stream>>>(cnt, excl, bsums, NN);
  scan2<<<1, 256, 0, stream>>>(bsums, 196);
  scan3<<<196, 256, 0, stream>>>(excl, bsums, cnt, row_start, dinv, NN);
  fill_kernel<<<(NE + 255) / 256, 256, 0, stream>>>(src, dst, row_start, dinv, fillcnt, csr, csrw);
  agg_kernel<<<NN / 2, 256, 0, stream>>>(x, csr, csrw, row_start, dinv, ax);
  kan_kernel<<<NN / 4, 256, 0, stream>>>(ax, gw, gb, pack0, pack1, out);
}